// Round 7
// baseline (4762.594 us; speedup 1.0000x reference)
//
#include <hip/hip_runtime.h>

#define BATCH 128
#define SEQ   512
#define EMB   512
#define HID   1024
#define NCLS  1000
#define NBLK  256    // 8 row groups x 32 blocks; rg = blk & 7 (XCD affinity heuristic)
#define TPB   256    // 4 waves; wave w = K-slice for MFMA, tile-owner w for epilogue

using short8 = __attribute__((ext_vector_type(8))) short;
using f32x4  = __attribute__((ext_vector_type(4))) float;
typedef unsigned long long u64;
typedef unsigned u32;

__device__ __forceinline__ short f2bf(float f) {
    unsigned u = __float_as_uint(f);
    unsigned r = (u + 0x7fffu + ((u >> 16) & 1u)) >> 16;   // RNE
    return (short)r;
}

// split fp32 into truncated-bf16 hi (bits 15:0) + bf16 lo (bits 31:16)
__device__ __forceinline__ u32 splitbf(float f) {
    unsigned u  = __float_as_uint(f);
    unsigned hi = u >> 16;
    float rem   = f - __uint_as_float(u & 0xffff0000u);   // exact
    unsigned lo = __float_as_uint(rem) >> 16;
    return hi | (lo << 16);
}

// ---- ws layout (bytes) ----
#define OFF_CP0 0u                 // packed (hi|lo) u32 exchange buf A [128][1024] = 512 KB (zeroed: tag 0 = step 0)
#define OFF_CP1 (512u << 10)       // exchange buf B (poison ok: tag bits of 0xAAAAAAAA = 2 != 1)
#define OFF_H   (1024u << 10)      // final fp32 h for FC
#define ZERO_I4 32768u             // zero cp0 only

__global__ void mgu_init(int4* __restrict__ ws4) {
    unsigned i = blockIdx.x * blockDim.x + threadIdx.x;
    if (i < ZERO_I4) ws4[i] = make_int4(0, 0, 0, 0);
}

// ---------------- sequential scan ----------------
// 256 blocks x 256 threads. rg = blk&7 (16 batch rows), pb = blk>>3 (col slice of 64 gate-cols).
// Wave w: (a) MFMA over K-slice w (12 hi-ks + 8 lo-ks) for ALL 4 col-tiles (weights: 320 VGPR/lane),
//         (b) epilogue owner of col-tile w. Partials reduced via 16 KB LDS.
// Exchange: packed u32 = (hi-bf16 | lo-bf16<<16), lo bits 1:0 carry tag = step&3 -> data is
// self-validating, no flags, no fences; agent-scope relaxed atomics (LLC coherence point).
__global__ __launch_bounds__(TPB, 1) void mgu_scan(
    const int* __restrict__ x, const float* __restrict__ emb,
    const float* __restrict__ Wz, const float* __restrict__ bz,
    const float* __restrict__ Wh, const float* __restrict__ bh,
    u32* __restrict__ cp0, u32* __restrict__ cp1, float* __restrict__ h)
{
    __shared__ short As[48 * 512];     // 48 KB hi fragments: ks 0..15 emb, 16..47 h-hi
    __shared__ short Al[32 * 512];     // 32 KB lo fragments: ks 0..31 (h only)
    __shared__ float Pp[16 * 64 * 4];  // 16 KB partial accumulators [w*4+c][lane][4]

    const int tid  = threadIdx.x;
    const int w    = tid >> 6;                 // wave 0..3
    const int lane = tid & 63;
    const int q    = lane >> 4;
    const int n    = lane & 15;
    const int blk  = blockIdx.x;
    const int rg   = blk & 7;
    const int r0   = rg << 4;
    const int pb   = blk >> 3;
    const int j0   = ((pb << 2) + w) << 3;     // epilogue tile-owner columns

    // ---- persistent weights: K-slice w for all 4 tiles (B-frag: B[k=q*8+e][col=lane&15]) ----
    short8 Bh[4][12];
    short8 Bl[4][8];
#pragma unroll
    for (int c = 0; c < 4; ++c) {
        const int jc = ((pb << 2) + c) << 3;
        const float* wp = ((n < 8) ? Wz : Wh) + jc + (n & 7);
#pragma unroll
        for (int i = 0; i < 12; ++i) {
            int ks = 12 * w + i;
            short8 f;
#pragma unroll
            for (int e = 0; e < 8; ++e)
                f[e] = f2bf(wp[(long)(ks * 32 + q * 8 + e) * HID]);
            Bh[c][i] = f;
        }
#pragma unroll
        for (int i = 0; i < 8; ++i) {
            int kl = 8 * w + i;
            short8 f;
#pragma unroll
            for (int e = 0; e < 8; ++e)
                f[e] = f2bf(wp[(long)(512 + kl * 32 + q * 8 + e) * HID]);
            Bl[c][i] = f;
        }
    }
    const float bzv = bz[j0 + (n & 7)];
    const float bhv = bh[j0 + (n & 7)];

    float hreg[4] = {0.f, 0.f, 0.f, 0.f};      // tile-owner state: rows r0+q*4+r2, col j0+n (n<8)

    auto stage_emb = [&](int tt) {             // emb fragments, slots 0..1023 (ks 0..15)
#pragma unroll
        for (int i = 0; i < 4; ++i) {
            int s  = tid + (i << 8);
            int nn = s & 15, qq = (s >> 4) & 3, ks = s >> 6;
            int tok = x[(r0 + nn) * SEQ + tt];
            const float4* ep = (const float4*)(emb + (long)tok * EMB + ks * 32 + qq * 8);
            float4 e0 = ep[0], e1 = ep[1];
            short8 v;
            v[0] = f2bf(e0.x); v[1] = f2bf(e0.y); v[2] = f2bf(e0.z); v[3] = f2bf(e0.w);
            v[4] = f2bf(e1.x); v[5] = f2bf(e1.y); v[6] = f2bf(e1.z); v[7] = f2bf(e1.w);
            *(short8*)&As[s * 8] = v;
        }
    };

    stage_emb(0);

    for (int t = 0; t < SEQ; ++t) {
        const u32* cpR = (t & 1) ? cp1 : cp0;
        u32*       cpW = (t & 1) ? cp0 : cp1;
        const unsigned tgR = (unsigned)(t & 3);
        const unsigned tgW = (unsigned)((t + 1) & 3);

        // ---- poll + load + stage h fragments (8 chunks of 4 u64 = 8 cols each) ----
        // prev iter's LDS reads of As/Al all complete before prev s3 -> no barrier needed here
        unsigned need = 0xffu;
        do {
#pragma unroll
            for (int i = 0; i < 8; ++i) {
                if (need & (1u << i)) {
                    int s  = 1024 + tid + (i << 8);
                    int nn = s & 15, qq = (s >> 4) & 3, ks = s >> 6;     // ks 16..47
                    int kc = (ks - 16) * 32 + qq * 8;
                    const u64* gp = (const u64*)(cpR + (r0 + nn) * HID + kc);
                    u64 va = __hip_atomic_load(gp + 0, __ATOMIC_RELAXED, __HIP_MEMORY_SCOPE_AGENT);
                    u64 vb = __hip_atomic_load(gp + 1, __ATOMIC_RELAXED, __HIP_MEMORY_SCOPE_AGENT);
                    u64 vc = __hip_atomic_load(gp + 2, __ATOMIC_RELAXED, __HIP_MEMORY_SCOPE_AGENT);
                    u64 vd = __hip_atomic_load(gp + 3, __ATOMIC_RELAXED, __HIP_MEMORY_SCOPE_AGENT);
                    bool ok = ((((unsigned)(va >> 16)) & 3u) == tgR) & ((((unsigned)(va >> 48)) & 3u) == tgR)
                            & ((((unsigned)(vb >> 16)) & 3u) == tgR) & ((((unsigned)(vb >> 48)) & 3u) == tgR)
                            & ((((unsigned)(vc >> 16)) & 3u) == tgR) & ((((unsigned)(vc >> 48)) & 3u) == tgR)
                            & ((((unsigned)(vd >> 16)) & 3u) == tgR) & ((((unsigned)(vd >> 48)) & 3u) == tgR);
                    if (ok) {
                        short8 hi8, lo8;
                        hi8[0] = (short)va;         lo8[0] = (short)(va >> 16);
                        hi8[1] = (short)(va >> 32); lo8[1] = (short)(va >> 48);
                        hi8[2] = (short)vb;         lo8[2] = (short)(vb >> 16);
                        hi8[3] = (short)(vb >> 32); lo8[3] = (short)(vb >> 48);
                        hi8[4] = (short)vc;         lo8[4] = (short)(vc >> 16);
                        hi8[5] = (short)(vc >> 32); lo8[5] = (short)(vc >> 48);
                        hi8[6] = (short)vd;         lo8[6] = (short)(vd >> 16);
                        hi8[7] = (short)(vd >> 32); lo8[7] = (short)(vd >> 48);
                        *(short8*)&As[s * 8]          = hi8;
                        *(short8*)&Al[(s - 1024) * 8] = lo8;
                        need &= ~(1u << i);
                    }
                }
            }
            if (!need) break;
            __builtin_amdgcn_s_sleep(1);
        } while (true);
        __syncthreads();                           // s2: staging visible

        // ---- MFMA over K-slice w, all 4 col-tiles (20 ds_reads, 80 MFMAs) ----
        f32x4 a0 = {0.f,0.f,0.f,0.f}, a1 = a0, a2 = a0, a3 = a0;
#pragma unroll
        for (int i = 0; i < 12; ++i) {
            short8 af = *(const short8*)&As[(12 * w + i) * 512 + lane * 8];
            a0 = __builtin_amdgcn_mfma_f32_16x16x32_bf16(af, Bh[0][i], a0, 0, 0, 0);
            a1 = __builtin_amdgcn_mfma_f32_16x16x32_bf16(af, Bh[1][i], a1, 0, 0, 0);
            a2 = __builtin_amdgcn_mfma_f32_16x16x32_bf16(af, Bh[2][i], a2, 0, 0, 0);
            a3 = __builtin_amdgcn_mfma_f32_16x16x32_bf16(af, Bh[3][i], a3, 0, 0, 0);
        }
#pragma unroll
        for (int i = 0; i < 8; ++i) {
            short8 af = *(const short8*)&Al[(8 * w + i) * 512 + lane * 8];
            a0 = __builtin_amdgcn_mfma_f32_16x16x32_bf16(af, Bl[0][i], a0, 0, 0, 0);
            a1 = __builtin_amdgcn_mfma_f32_16x16x32_bf16(af, Bl[1][i], a1, 0, 0, 0);
            a2 = __builtin_amdgcn_mfma_f32_16x16x32_bf16(af, Bl[2][i], a2, 0, 0, 0);
            a3 = __builtin_amdgcn_mfma_f32_16x16x32_bf16(af, Bl[3][i], a3, 0, 0, 0);
        }
        *(f32x4*)&Pp[((w * 4 + 0) * 64 + lane) * 4] = a0;
        *(f32x4*)&Pp[((w * 4 + 1) * 64 + lane) * 4] = a1;
        *(f32x4*)&Pp[((w * 4 + 2) * 64 + lane) * 4] = a2;
        *(f32x4*)&Pp[((w * 4 + 3) * 64 + lane) * 4] = a3;
        __syncthreads();                           // s3: partials visible

        // ---- reduce own tile w across the 4 K-slices ----
        f32x4 p0 = *(const f32x4*)&Pp[((0 * 4 + w) * 64 + lane) * 4];
        f32x4 p1 = *(const f32x4*)&Pp[((1 * 4 + w) * 64 + lane) * 4];
        f32x4 p2 = *(const f32x4*)&Pp[((2 * 4 + w) * 64 + lane) * 4];
        f32x4 p3 = *(const f32x4*)&Pp[((3 * 4 + w) * 64 + lane) * 4];
        f32x4 acc = (p0 + p1) + (p2 + p3);

        // z-pre lanes n<8, h~-pre lanes n>=8 (same col); partner = lane^8
        float o0 = __shfl_xor(acc[0], 8, 64);
        float o1 = __shfl_xor(acc[1], 8, 64);
        float o2 = __shfl_xor(acc[2], 8, 64);
        float o3 = __shfl_xor(acc[3], 8, 64);

        if (n < 8) {
            float zp[4] = {acc[0], acc[1], acc[2], acc[3]};
            float tp[4] = {o0, o1, o2, o3};
            float hn[4];
#pragma unroll
            for (int r2 = 0; r2 < 4; ++r2) {
                float z  = 1.f / (1.f + __expf(-(zp[r2] + bzv)));
                float ht = tanhf(tp[r2] + bhv);
                float ho = hreg[r2];
                hn[r2] = ho + z * (ht - ho);
                hreg[r2] = hn[r2];
            }
            const int j = j0 + n;
            if (t < SEQ - 1) {
                u32 p[4];
#pragma unroll
                for (int r2 = 0; r2 < 4; ++r2)
                    p[r2] = (splitbf(hn[r2]) & 0xfffcffffu) | (tgW << 16);   // tag in lo bits 1:0
                u32 pv0 = __shfl_xor(p[0], 1, 64);
                u32 pv1 = __shfl_xor(p[1], 1, 64);
                u32 pv2 = __shfl_xor(p[2], 1, 64);
                u32 pv3 = __shfl_xor(p[3], 1, 64);
                int rbase = (r0 + q * 4) * HID;
                if ((n & 1) == 0) {
                    u64 w0 = (u64)p[0] | ((u64)pv0 << 32);
                    u64 w1 = (u64)p[1] | ((u64)pv1 << 32);
                    __hip_atomic_store((u64*)(cpW + rbase + j),       w0, __ATOMIC_RELAXED, __HIP_MEMORY_SCOPE_AGENT);
                    __hip_atomic_store((u64*)(cpW + rbase + HID + j), w1, __ATOMIC_RELAXED, __HIP_MEMORY_SCOPE_AGENT);
                } else {
                    u64 w2 = (u64)pv2 | ((u64)p[2] << 32);
                    u64 w3 = (u64)pv3 | ((u64)p[3] << 32);
                    __hip_atomic_store((u64*)(cpW + rbase + 2 * HID + j - 1), w2, __ATOMIC_RELAXED, __HIP_MEMORY_SCOPE_AGENT);
                    __hip_atomic_store((u64*)(cpW + rbase + 3 * HID + j - 1), w3, __ATOMIC_RELAXED, __HIP_MEMORY_SCOPE_AGENT);
                }
            } else {
#pragma unroll
                for (int r2 = 0; r2 < 4; ++r2)
                    h[(r0 + q * 4 + r2) * HID + j] = hn[r2];   // final state: kernel-end flush
            }
        }

        if (t < SEQ - 1) stage_emb(t + 1);         // As emb slots: prev reads done before s3
    }
}

// ---------------- final FC: logits = h @ Wfc + bfc, full fp32 ----------------
__global__ __launch_bounds__(256) void mgu_fc(const float* __restrict__ h,
                                              const float* __restrict__ Wfc,
                                              const float* __restrict__ bfc,
                                              float* __restrict__ out) {
    __shared__ float hs[BATCH][65];
    const int tid = threadIdx.x;
    const int n0  = blockIdx.x * 8;
    const int b   = tid & 127;
    const int nn  = tid >> 7;
    const int nc  = n0 + nn * 4;
    float acc0 = 0.f, acc1 = 0.f, acc2 = 0.f, acc3 = 0.f;

    for (int k0 = 0; k0 < HID; k0 += 64) {
        __syncthreads();
#pragma unroll
        for (int jj = 0; jj < 8; ++jj) {
            int idx = tid + jj * 256;
            int bb  = idx >> 4;
            int kk  = (idx & 15) << 2;
            const float4 v = *(const float4*)(h + bb * HID + k0 + kk);
            hs[bb][kk] = v.x; hs[bb][kk + 1] = v.y; hs[bb][kk + 2] = v.z; hs[bb][kk + 3] = v.w;
        }
        __syncthreads();
#pragma unroll 8
        for (int k = 0; k < 64; ++k) {
            float hv = hs[b][k];
            const float4 wv = *(const float4*)(Wfc + (long)(k0 + k) * NCLS + nc);
            acc0 += hv * wv.x; acc1 += hv * wv.y; acc2 += hv * wv.z; acc3 += hv * wv.w;
        }
    }
    float* op = out + b * NCLS + nc;
    op[0] = acc0 + bfc[nc + 0];
    op[1] = acc1 + bfc[nc + 1];
    op[2] = acc2 + bfc[nc + 2];
    op[3] = acc3 + bfc[nc + 3];
}

extern "C" void kernel_launch(void* const* d_in, const int* in_sizes, int n_in,
                              void* d_out, int out_size, void* d_ws, size_t ws_size,
                              hipStream_t stream) {
    const int*   x   = (const int*)  d_in[0];
    const float* emb = (const float*)d_in[1];
    const float* Wz  = (const float*)d_in[2];
    const float* bz  = (const float*)d_in[3];
    const float* Wh  = (const float*)d_in[4];
    const float* bh  = (const float*)d_in[5];
    const float* Wfc = (const float*)d_in[6];
    const float* bfc = (const float*)d_in[7];
    float* out = (float*)d_out;

    char* ws = (char*)d_ws;
    u32*   cp0 = (u32*)  (ws + OFF_CP0);
    u32*   cp1 = (u32*)  (ws + OFF_CP1);
    float* h   = (float*)(ws + OFF_H);

    mgu_init<<<128, 256, 0, stream>>>((int4*)ws);   // zero cp0 (tag 0 == step 0)

    mgu_scan<<<NBLK, TPB, 0, stream>>>(x, emb, Wz, bz, Wh, bh, cp0, cp1, h);

    mgu_fc<<<125, 256, 0, stream>>>(h, Wfc, bfc, out);
}

// Round 8
// 4732.510 us; speedup vs baseline: 1.0064x; 1.0064x over previous
//
#include <hip/hip_runtime.h>

#define BATCH 128
#define SEQ   512
#define EMB   512
#define HID   1024
#define NCLS  1000
#define NBLK  256    // 8 row groups x 32 blocks; rg = blk & 7 (XCD affinity heuristic)
#define TPB   256    // 4 waves; wave w = K-interleave slice (ks%4==w) + epilogue tile w

using short8 = __attribute__((ext_vector_type(8))) short;
using f32x4  = __attribute__((ext_vector_type(4))) float;
typedef unsigned long long u64;
typedef unsigned u32;
using u32x4 = __attribute__((ext_vector_type(4))) u32;

__device__ __forceinline__ short f2bf(float f) {
    unsigned u = __float_as_uint(f);
    unsigned r = (u + 0x7fffu + ((u >> 16) & 1u)) >> 16;   // RNE
    return (short)r;
}

// split fp32 into truncated-bf16 hi (bits 15:0) + bf16 lo (bits 31:16)
__device__ __forceinline__ u32 splitbf(float f) {
    unsigned u  = __float_as_uint(f);
    unsigned hi = u >> 16;
    float rem   = f - __uint_as_float(u & 0xffff0000u);   // exact
    unsigned lo = __float_as_uint(rem) >> 16;
    return hi | (lo << 16);
}

// L1-bypassing, L2-served 32B chunk load (sc0): fast path of the exchange poll
__device__ __forceinline__ void load_chunk_sc0(const u32* p, u32x4& x, u32x4& y) {
    asm volatile("global_load_dwordx4 %0, %2, off sc0\n\t"
                 "global_load_dwordx4 %1, %2, off offset:16 sc0\n\t"
                 "s_waitcnt vmcnt(0)"
                 : "=&v"(x), "=&v"(y) : "v"(p) : "memory");
}

// ---- ws layout (bytes) ----
#define OFF_CP0 0u                 // packed (hi|lo|tag) u32 exchange buf A [128][1024] = 512 KB (zeroed: tag 0)
#define OFF_CP1 (512u << 10)       // exchange buf B (0xAA poison tag = 2, never expected at first reads)
#define OFF_H   (1024u << 10)      // final fp32 h for FC
#define ZERO_I4 32768u             // zero cp0 only

__global__ void mgu_init(int4* __restrict__ ws4) {
    unsigned i = blockIdx.x * blockDim.x + threadIdx.x;
    if (i < ZERO_I4) ws4[i] = make_int4(0, 0, 0, 0);
}

// ---------------- sequential scan ----------------
// 256 blocks x 256 threads. rg = blk&7 (16 batch rows), pb = blk>>3 (64 gate-cols slice).
// Wave w: MFMA over ks ≡ w (mod 4) for all 4 col-tiles; lo-correction frag kl shares the
// hi B-frag of ks=kl+16 (also ≡ w mod 4) -> 48 short8 = 192 weight VGPRs/lane, no spill.
// Exchange: packed u32 (hi-bf16 | lo-bf16<<16), tag=step&3 in lo bits 1:0 (self-validating).
// Producer dual-store: plain store (dirty in local/shared L2) + agent atomic (LLC escape).
// Consumer poll: sc0 loads (L2-served); after 4 passes escalate to agent/LLC. No fences.
__global__ __launch_bounds__(TPB, 1) void mgu_scan(
    const int* __restrict__ x, const float* __restrict__ emb,
    const float* __restrict__ Wz, const float* __restrict__ bz,
    const float* __restrict__ Wh, const float* __restrict__ bh,
    u32* __restrict__ cp0, u32* __restrict__ cp1, float* __restrict__ h)
{
    __shared__ short As[48 * 512];     // 48 KB hi fragments: ks 0..15 emb, 16..47 h-hi
    __shared__ short Al[32 * 512];     // 32 KB lo fragments: kl 0..31
    __shared__ float Pp[16 * 64 * 4];  // 16 KB partials [w*4+c][lane][4]

    const int tid  = threadIdx.x;
    const int w    = tid >> 6;                 // wave 0..3
    const int lane = tid & 63;
    const int q    = lane >> 4;
    const int n    = lane & 15;
    const int blk  = blockIdx.x;
    const int rg   = blk & 7;
    const int r0   = rg << 4;
    const int pb   = blk >> 3;
    const int j0   = ((pb << 2) + w) << 3;     // epilogue tile-owner columns

    // ---- persistent weights: ks = 4*j + w, j=0..11, for all 4 col-tiles ----
    short8 Bh[4][12];
#pragma unroll
    for (int c = 0; c < 4; ++c) {
        const int jc = ((pb << 2) + c) << 3;
        const float* wp = ((n < 8) ? Wz : Wh) + jc + (n & 7);
#pragma unroll
        for (int j = 0; j < 12; ++j) {
            int ks = 4 * j + w;
            short8 f;
#pragma unroll
            for (int e = 0; e < 8; ++e)
                f[e] = f2bf(wp[(long)(ks * 32 + q * 8 + e) * HID]);
            Bh[c][j] = f;
        }
    }
    const float bzv = bz[j0 + (n & 7)];
    const float bhv = bh[j0 + (n & 7)];

    float hreg[4] = {0.f, 0.f, 0.f, 0.f};      // tile-owner state: rows r0+q*4+r2, col j0+n (n<8)

    auto stage_emb = [&](int tt) {             // emb fragments, slots 0..1023 (ks 0..15)
#pragma unroll
        for (int i = 0; i < 4; ++i) {
            int s  = tid + (i << 8);
            int nn = s & 15, qq = (s >> 4) & 3, ks = s >> 6;
            int tok = x[(r0 + nn) * SEQ + tt];
            const float4* ep = (const float4*)(emb + (long)tok * EMB + ks * 32 + qq * 8);
            float4 e0 = ep[0], e1 = ep[1];
            short8 v;
            v[0] = f2bf(e0.x); v[1] = f2bf(e0.y); v[2] = f2bf(e0.z); v[3] = f2bf(e0.w);
            v[4] = f2bf(e1.x); v[5] = f2bf(e1.y); v[6] = f2bf(e1.z); v[7] = f2bf(e1.w);
            *(short8*)&As[s * 8] = v;
        }
    };

    stage_emb(0);

    for (int t = 0; t < SEQ; ++t) {
        const u32* cpR = (t & 1) ? cp1 : cp0;
        u32*       cpW = (t & 1) ? cp0 : cp1;
        const unsigned tgR = (unsigned)(t & 3);
        const unsigned tgW = (unsigned)((t + 1) & 3);

        // ---- poll + stage h fragments (8 chunks x 8 u32 = 8 cols each) ----
        unsigned need = 0xffu;
        int pass = 0;
        do {
#pragma unroll
            for (int i = 0; i < 8; ++i) {
                if (need & (1u << i)) {
                    int s  = 1024 + tid + (i << 8);
                    int nn = s & 15, qq = (s >> 4) & 3, ks = s >> 6;     // ks 16..47
                    const u32* gp = cpR + (r0 + nn) * HID + ((ks - 16) * 32 + qq * 8);
                    u32x4 va, vb;
                    if (pass < 4) {
                        load_chunk_sc0(gp, va, vb);                      // L2 fast path
                    } else {                                             // LLC escape hatch
                        const u64* g8 = (const u64*)gp;
                        u64 a = __hip_atomic_load(g8 + 0, __ATOMIC_RELAXED, __HIP_MEMORY_SCOPE_AGENT);
                        u64 b = __hip_atomic_load(g8 + 1, __ATOMIC_RELAXED, __HIP_MEMORY_SCOPE_AGENT);
                        u64 c = __hip_atomic_load(g8 + 2, __ATOMIC_RELAXED, __HIP_MEMORY_SCOPE_AGENT);
                        u64 d = __hip_atomic_load(g8 + 3, __ATOMIC_RELAXED, __HIP_MEMORY_SCOPE_AGENT);
                        va[0] = (u32)a; va[1] = (u32)(a >> 32); va[2] = (u32)b; va[3] = (u32)(b >> 32);
                        vb[0] = (u32)c; vb[1] = (u32)(c >> 32); vb[2] = (u32)d; vb[3] = (u32)(d >> 32);
                    }
                    bool ok = (((va[0] >> 16) & 3u) == tgR) & (((va[1] >> 16) & 3u) == tgR)
                            & (((va[2] >> 16) & 3u) == tgR) & (((va[3] >> 16) & 3u) == tgR)
                            & (((vb[0] >> 16) & 3u) == tgR) & (((vb[1] >> 16) & 3u) == tgR)
                            & (((vb[2] >> 16) & 3u) == tgR) & (((vb[3] >> 16) & 3u) == tgR);
                    if (ok) {
                        short8 hi8, lo8;
#pragma unroll
                        for (int e = 0; e < 4; ++e) {
                            hi8[e]     = (short)(va[e] & 0xffffu);  lo8[e]     = (short)(va[e] >> 16);
                            hi8[e + 4] = (short)(vb[e] & 0xffffu);  lo8[e + 4] = (short)(vb[e] >> 16);
                        }
                        *(short8*)&As[s * 8]          = hi8;
                        *(short8*)&Al[(s - 1024) * 8] = lo8;
                        need &= ~(1u << i);
                    }
                }
            }
            if (!need) break;
            ++pass;
            __builtin_amdgcn_s_sleep(1);
        } while (true);
        __syncthreads();                           // s2: staging visible

        // ---- MFMA over ks ≡ w (mod 4), all 4 col-tiles (20 ds_reads, 80 MFMAs) ----
        f32x4 a0 = {0.f,0.f,0.f,0.f}, a1 = a0, a2 = a0, a3 = a0;
#pragma unroll
        for (int j = 0; j < 12; ++j) {
            short8 af = *(const short8*)&As[(4 * j + w) * 512 + lane * 8];
            a0 = __builtin_amdgcn_mfma_f32_16x16x32_bf16(af, Bh[0][j], a0, 0, 0, 0);
            a1 = __builtin_amdgcn_mfma_f32_16x16x32_bf16(af, Bh[1][j], a1, 0, 0, 0);
            a2 = __builtin_amdgcn_mfma_f32_16x16x32_bf16(af, Bh[2][j], a2, 0, 0, 0);
            a3 = __builtin_amdgcn_mfma_f32_16x16x32_bf16(af, Bh[3][j], a3, 0, 0, 0);
        }
#pragma unroll
        for (int i = 0; i < 8; ++i) {              // lo: kl = 4i+w shares Bh[..][i+4] (ks=kl+16)
            short8 al = *(const short8*)&Al[(4 * i + w) * 512 + lane * 8];
            a0 = __builtin_amdgcn_mfma_f32_16x16x32_bf16(al, Bh[0][i + 4], a0, 0, 0, 0);
            a1 = __builtin_amdgcn_mfma_f32_16x16x32_bf16(al, Bh[1][i + 4], a1, 0, 0, 0);
            a2 = __builtin_amdgcn_mfma_f32_16x16x32_bf16(al, Bh[2][i + 4], a2, 0, 0, 0);
            a3 = __builtin_amdgcn_mfma_f32_16x16x32_bf16(al, Bh[3][i + 4], a3, 0, 0, 0);
        }
        *(f32x4*)&Pp[((w * 4 + 0) * 64 + lane) * 4] = a0;
        *(f32x4*)&Pp[((w * 4 + 1) * 64 + lane) * 4] = a1;
        *(f32x4*)&Pp[((w * 4 + 2) * 64 + lane) * 4] = a2;
        *(f32x4*)&Pp[((w * 4 + 3) * 64 + lane) * 4] = a3;
        __syncthreads();                           // s3: partials visible

        // ---- reduce own tile w across the 4 K-slices ----
        f32x4 p0 = *(const f32x4*)&Pp[((0 * 4 + w) * 64 + lane) * 4];
        f32x4 p1 = *(const f32x4*)&Pp[((1 * 4 + w) * 64 + lane) * 4];
        f32x4 p2 = *(const f32x4*)&Pp[((2 * 4 + w) * 64 + lane) * 4];
        f32x4 p3 = *(const f32x4*)&Pp[((3 * 4 + w) * 64 + lane) * 4];
        f32x4 acc = (p0 + p1) + (p2 + p3);

        // z-pre lanes n<8, h~-pre lanes n>=8 (same col); partner = lane^8
        float o0 = __shfl_xor(acc[0], 8, 64);
        float o1 = __shfl_xor(acc[1], 8, 64);
        float o2 = __shfl_xor(acc[2], 8, 64);
        float o3 = __shfl_xor(acc[3], 8, 64);

        if (n < 8) {
            float zp[4] = {acc[0], acc[1], acc[2], acc[3]};
            float tp[4] = {o0, o1, o2, o3};
            float hn[4];
#pragma unroll
            for (int r2 = 0; r2 < 4; ++r2) {
                float z  = 1.f / (1.f + __expf(-(zp[r2] + bzv)));
                float ht = tanhf(tp[r2] + bhv);
                float ho = hreg[r2];
                hn[r2] = ho + z * (ht - ho);
                hreg[r2] = hn[r2];
            }
            const int j = j0 + n;
            if (t < SEQ - 1) {
                u32 p[4];
#pragma unroll
                for (int r2 = 0; r2 < 4; ++r2)
                    p[r2] = (splitbf(hn[r2]) & 0xfffcffffu) | (tgW << 16);   // tag in lo bits 1:0
                u32 pv0 = __shfl_xor(p[0], 1, 64);
                u32 pv1 = __shfl_xor(p[1], 1, 64);
                u32 pv2 = __shfl_xor(p[2], 1, 64);
                u32 pv3 = __shfl_xor(p[3], 1, 64);
                int rbase = (r0 + q * 4) * HID;
                u64* d0; u64* d1; u64 w0, w1;
                if ((n & 1) == 0) {
                    w0 = (u64)p[0] | ((u64)pv0 << 32);
                    w1 = (u64)p[1] | ((u64)pv1 << 32);
                    d0 = (u64*)(cpW + rbase + j);
                    d1 = (u64*)(cpW + rbase + HID + j);
                } else {
                    w0 = (u64)pv2 | ((u64)p[2] << 32);
                    w1 = (u64)pv3 | ((u64)p[3] << 32);
                    d0 = (u64*)(cpW + rbase + 2 * HID + j - 1);
                    d1 = (u64*)(cpW + rbase + 3 * HID + j - 1);
                }
                *(volatile u64*)d0 = w0;           // fast copy: dirty line in local L2
                *(volatile u64*)d1 = w1;
                __hip_atomic_store(d0, w0, __ATOMIC_RELAXED, __HIP_MEMORY_SCOPE_AGENT);  // LLC copy
                __hip_atomic_store(d1, w1, __ATOMIC_RELAXED, __HIP_MEMORY_SCOPE_AGENT);
            } else {
#pragma unroll
                for (int r2 = 0; r2 < 4; ++r2)
                    h[(r0 + q * 4 + r2) * HID + j] = hn[r2];   // final state: kernel-end flush
            }
        }

        if (t < SEQ - 1) stage_emb(t + 1);         // emb slots: all As readers passed s3
    }
}

// ---------------- final FC: logits = h @ Wfc + bfc, full fp32 ----------------
__global__ __launch_bounds__(256) void mgu_fc(const float* __restrict__ h,
                                              const float* __restrict__ Wfc,
                                              const float* __restrict__ bfc,
                                              float* __restrict__ out) {
    __shared__ float hs[BATCH][65];
    const int tid = threadIdx.x;
    const int n0  = blockIdx.x * 8;
    const int b   = tid & 127;
    const int nn  = tid >> 7;
    const int nc  = n0 + nn * 4;
    float acc0 = 0.f, acc1 = 0.f, acc2 = 0.f, acc3 = 0.f;

    for (int k0 = 0; k0 < HID; k0 += 64) {
        __syncthreads();
#pragma unroll
        for (int jj = 0; jj < 8; ++jj) {
            int idx = tid + jj * 256;
            int bb  = idx >> 4;
            int kk  = (idx & 15) << 2;
            const float4 v = *(const float4*)(h + bb * HID + k0 + kk);
            hs[bb][kk] = v.x; hs[bb][kk + 1] = v.y; hs[bb][kk + 2] = v.z; hs[bb][kk + 3] = v.w;
        }
        __syncthreads();
#pragma unroll 8
        for (int k = 0; k < 64; ++k) {
            float hv = hs[b][k];
            const float4 wv = *(const float4*)(Wfc + (long)(k0 + k) * NCLS + nc);
            acc0 += hv * wv.x; acc1 += hv * wv.y; acc2 += hv * wv.z; acc3 += hv * wv.w;
        }
    }
    float* op = out + b * NCLS + nc;
    op[0] = acc0 + bfc[nc + 0];
    op[1] = acc1 + bfc[nc + 1];
    op[2] = acc2 + bfc[nc + 2];
    op[3] = acc3 + bfc[nc + 3];
}

extern "C" void kernel_launch(void* const* d_in, const int* in_sizes, int n_in,
                              void* d_out, int out_size, void* d_ws, size_t ws_size,
                              hipStream_t stream) {
    const int*   x   = (const int*)  d_in[0];
    const float* emb = (const float*)d_in[1];
    const float* Wz  = (const float*)d_in[2];
    const float* bz  = (const float*)d_in[3];
    const float* Wh  = (const float*)d_in[4];
    const float* bh  = (const float*)d_in[5];
    const float* Wfc = (const float*)d_in[6];
    const float* bfc = (const float*)d_in[7];
    float* out = (float*)d_out;

    char* ws = (char*)d_ws;
    u32*   cp0 = (u32*)  (ws + OFF_CP0);
    u32*   cp1 = (u32*)  (ws + OFF_CP1);
    float* h   = (float*)(ws + OFF_H);

    mgu_init<<<128, 256, 0, stream>>>((int4*)ws);   // zero cp0 (tag 0 == step 0)

    mgu_scan<<<NBLK, TPB, 0, stream>>>(x, emb, Wz, bz, Wh, bh, cp0, cp1, h);

    mgu_fc<<<125, 256, 0, stream>>>(h, Wfc, bfc, out);
}